// Round 1
// baseline (109.124 us; speedup 1.0000x reference)
//
#include <hip/hip_runtime.h>
#include <math.h>

#define N_RINGS  10
#define N_ANGLES 36
#define NP       (N_RINGS * N_ANGLES)   // 360 points per batch
#define PI_APPROX 3.1415926f

#define CHUNK 256     // targets staged per block
#define BLOCK 384     // 6 waves; threads 0..359 each own one point

// ---------------- init: ws[b*NP+p] = +inf (as uint bits) ----------------
__global__ void init_ws(unsigned int* __restrict__ ws, int n) {
    int i = blockIdx.x * blockDim.x + threadIdx.x;
    if (i < n) ws[i] = 0x7F800000u;  // +inf, bit-comparable for d2 >= 0
}

// ---------------- main: per-(batch, target-chunk) block -----------------
// Thread t (<360) owns generated point p=t; keeps running min in a register
// while scanning the LDS-staged target chunk (wave-uniform reads = broadcast).
__global__ __launch_bounds__(BLOCK) void chamfer_min(
    const float* __restrict__ pred,    // B x N_RINGS
    const float* __restrict__ target,  // B x N x 3
    unsigned int* __restrict__ ws,     // B x NP   (min d2 as uint bits)
    int N, int chunksPerBatch)
{
    __shared__ float4 t4[CHUNK];       // x, y, z, |t|^2
    __shared__ float cs_c[N_ANGLES], cs_s[N_ANGLES];

    const int b   = blockIdx.x / chunksPerBatch;
    const int c   = blockIdx.x % chunksPerBatch;
    const int n0  = c * CHUNK;
    const int tid = threadIdx.x;
    const int cnt = min(CHUNK, N - n0);

    // angle table (double-precision trig on the fp32 angle, matches numpy f32)
    if (tid < N_ANGLES) {
        float angf = (float)(10 * tid) * (2.0f * PI_APPROX / 360.0f);
        double ang = (double)angf;
        cs_c[tid] = (float)cos(ang);
        cs_s[tid] = (float)sin(ang);
    }
    // stage target chunk, coalesced-ish (12B/thread)
    for (int i = tid; i < cnt; i += BLOCK) {
        const float* t = target + ((size_t)b * N + (size_t)(n0 + i)) * 3;
        float x = t[0], y = t[1], z = t[2];
        t4[i] = make_float4(x, y, z, x * x + y * y + z * z);
    }
    __syncthreads();

    if (tid < NP) {
        const int j = tid / N_ANGLES;   // ring
        const int a = tid % N_ANGLES;   // angle
        const float r  = pred[b * N_RINGS + j];
        const float px = -r * cs_c[a] + 0.04f;
        const float py = 0.15f * (float)j - 0.7f;
        const float pz = r * cs_s[a];
        const float pp2 = px * px + py * py + pz * pz;

        float m = 3.4e38f;
        #pragma unroll 8
        for (int k = 0; k < cnt; ++k) {
            float4 t = t4[k];
            float dot = px * t.x + py * t.y + pz * t.z;      // fma chain
            float d   = pp2 + t.w - 2.0f * dot;
            d = fmaxf(d, 0.0f);                               // ref clamps before min
            m = fminf(m, d);
        }
        atomicMin(&ws[b * NP + tid], __float_as_uint(m));
    }
}

// ---------------- final: mean over B*NP mins, double accumulation -------
__global__ void reduce_mean(const unsigned int* __restrict__ ws,
                            float* __restrict__ out, int count) {
    __shared__ double sm[8];
    const int tid = threadIdx.x;
    double s = 0.0;
    for (int i = tid; i < count; i += blockDim.x)
        s += (double)__uint_as_float(ws[i]);
    #pragma unroll
    for (int off = 32; off > 0; off >>= 1)
        s += __shfl_down(s, off, 64);
    if ((tid & 63) == 0) sm[tid >> 6] = s;
    __syncthreads();
    if (tid == 0) {
        double tot = 0.0;
        const int nw = (int)blockDim.x >> 6;
        for (int w = 0; w < nw; ++w) tot += sm[w];
        out[0] = (float)(tot / (double)count);
    }
}

extern "C" void kernel_launch(void* const* d_in, const int* in_sizes, int n_in,
                              void* d_out, int out_size, void* d_ws, size_t ws_size,
                              hipStream_t stream) {
    const float* pred   = (const float*)d_in[0];
    const float* target = (const float*)d_in[1];
    // d_in[2] (trans_feat) is unused by the reference.

    const int B = in_sizes[0] / N_RINGS;
    const int N = in_sizes[1] / (3 * B);
    const int count  = B * NP;
    const int chunks = (N + CHUNK - 1) / CHUNK;

    unsigned int* ws = (unsigned int*)d_ws;
    float* out = (float*)d_out;

    hipLaunchKernelGGL(init_ws, dim3((count + 255) / 256), dim3(256), 0, stream,
                       ws, count);
    hipLaunchKernelGGL(chamfer_min, dim3(B * chunks), dim3(BLOCK), 0, stream,
                       pred, target, ws, N, chunks);
    hipLaunchKernelGGL(reduce_mean, dim3(1), dim3(512), 0, stream,
                       ws, out, count);
}

// Round 2
// 96.176 us; speedup vs baseline: 1.1346x; 1.1346x over previous
//
#include <hip/hip_runtime.h>
#include <math.h>
#include <float.h>

#define N_RINGS  10
#define N_ANGLES 36
#define NP       (N_RINGS * N_ANGLES)   // 360 points per batch
#define PI_APPROX 3.1415926f

#define BLOCK  256        // 4 waves
#define WPB    4          // waves per block
#define CHUNK  1024       // targets staged per block
#define PPT    6          // point-slots per thread-lane: 6*64 = 384 >= 360

// ---------------- kernel A: per-(batch, target-chunk-group) block --------
// Each lane owns 6 point slots (l, l+64, ..., l+320). Waves split the staged
// CHUNK of targets; each wave-uniform ds_read_b128 broadcast feeds 6 points
// (24 FMA/MIN) instead of 1 -> LDS return BW amortized 6x.
// Block writes one clamped partial min per point to ws[(b*NP+p)*chunks + cg].
__global__ __launch_bounds__(BLOCK) void chamfer_partial(
    const float* __restrict__ pred,    // B x N_RINGS
    const float* __restrict__ target,  // B x N x 3
    float* __restrict__ ws,            // B x NP x chunks partial mins
    int N, int chunks)
{
    __shared__ float4 t4[CHUNK];          // x, y, z, |t|^2
    __shared__ float  pm[WPB * NP];       // per-wave clamped partial mins
    __shared__ float  cs_c[N_ANGLES], cs_s[N_ANGLES];

    const int b   = blockIdx.x / chunks;
    const int cg  = blockIdx.x % chunks;
    const int n0  = cg * CHUNK;
    const int tid = threadIdx.x;
    const int cnt = min(CHUNK, N - n0);

    if (tid < N_ANGLES) {
        float angf = (float)(10 * tid) * (2.0f * PI_APPROX / 360.0f);
        double ang = (double)angf;
        cs_c[tid] = (float)cos(ang);
        cs_s[tid] = (float)sin(ang);
    }
    // stage target chunk: x, y, z, |t|^2
    for (int i = tid; i < cnt; i += BLOCK) {
        const float* t = target + ((size_t)b * N + (size_t)(n0 + i)) * 3;
        float x = t[0], y = t[1], z = t[2];
        t4[i] = make_float4(x, y, z, x * x + y * y + z * z);
    }
    __syncthreads();

    const int lane = tid & 63;
    const int w    = tid >> 6;

    // per-slot point setup: q = -2*p so inner pair = fma(qz,z, fma(qy,y, fma(qx,x, t2)))
    float qx[PPT], qy[PPT], qz[PPT], pp2[PPT], m[PPT];
    #pragma unroll
    for (int k = 0; k < PPT; ++k) {
        int s = lane + 64 * k;          // point slot
        int j = s / N_ANGLES;
        int a = s - j * N_ANGLES;
        int jc = (j < N_RINGS) ? j : (N_RINGS - 1);   // clamp for dummy slots
        float r  = pred[b * N_RINGS + jc];
        float px = -r * cs_c[a] + 0.04f;
        float py = 0.15f * (float)jc - 0.7f;
        float pz = r * cs_s[a];
        pp2[k] = px * px + py * py + pz * pz;
        qx[k] = -2.0f * px;
        qy[k] = -2.0f * py;
        qz[k] = -2.0f * pz;
        m[k]  = FLT_MAX;
    }

    // waves split the chunk; t4[k] is wave-uniform -> broadcast read
    #pragma unroll 4
    for (int k = w; k < cnt; k += WPB) {
        float4 t = t4[k];
        #pragma unroll
        for (int i = 0; i < PPT; ++i) {
            float h = fmaf(qz[i], t.z, t.w);
            h = fmaf(qy[i], t.y, h);
            h = fmaf(qx[i], t.x, h);
            m[i] = fminf(m[i], h);
        }
    }

    // finalize (add pp2, clamp) and publish per-wave partials
    #pragma unroll
    for (int k = 0; k < PPT; ++k) {
        int s = lane + 64 * k;
        if (s < NP) pm[w * NP + s] = fmaxf(pp2[k] + m[k], 0.0f);
    }
    __syncthreads();

    // cross-wave min, write per-block partial
    for (int p = tid; p < NP; p += BLOCK) {
        float v = fminf(fminf(pm[p], pm[NP + p]),
                        fminf(pm[2 * NP + p], pm[3 * NP + p]));
        ws[((size_t)(b * NP + p)) * chunks + cg] = v;
    }
}

// ---------------- kernel B: min over chunk partials, mean (double) -------
__global__ __launch_bounds__(1024) void reduce_mean(
    const float* __restrict__ ws, float* __restrict__ out,
    int count, int chunks)
{
    __shared__ double sm[16];
    const int tid = threadIdx.x;
    double s = 0.0;
    for (int i = tid; i < count; i += 1024) {
        const float* base = ws + (size_t)i * chunks;
        float mn = FLT_MAX;
        int c = 0;
        for (; c + 4 <= chunks; c += 4) {
            float4 v = *(const float4*)(base + c);
            mn = fminf(mn, fminf(fminf(v.x, v.y), fminf(v.z, v.w)));
        }
        for (; c < chunks; ++c) mn = fminf(mn, base[c]);
        s += (double)mn;
    }
    #pragma unroll
    for (int off = 32; off > 0; off >>= 1)
        s += __shfl_down(s, off, 64);
    if ((tid & 63) == 0) sm[tid >> 6] = s;
    __syncthreads();
    if (tid == 0) {
        double tot = 0.0;
        for (int wv = 0; wv < 16; ++wv) tot += sm[wv];
        out[0] = (float)(tot / (double)count);
    }
}

extern "C" void kernel_launch(void* const* d_in, const int* in_sizes, int n_in,
                              void* d_out, int out_size, void* d_ws, size_t ws_size,
                              hipStream_t stream) {
    const float* pred   = (const float*)d_in[0];
    const float* target = (const float*)d_in[1];
    // d_in[2] (trans_feat) unused by the reference.

    const int B = in_sizes[0] / N_RINGS;
    const int N = in_sizes[1] / (3 * B);
    const int chunks = (N + CHUNK - 1) / CHUNK;   // 16 for N=16384
    const int count  = B * NP;                    // 11520

    float* ws  = (float*)d_ws;
    float* out = (float*)d_out;

    hipLaunchKernelGGL(chamfer_partial, dim3(B * chunks), dim3(BLOCK), 0, stream,
                       pred, target, ws, N, chunks);
    hipLaunchKernelGGL(reduce_mean, dim3(1), dim3(1024), 0, stream,
                       ws, out, count, chunks);
}

// Round 3
// 85.891 us; speedup vs baseline: 1.2705x; 1.1198x over previous
//
#include <hip/hip_runtime.h>
#include <math.h>
#include <float.h>

#define N_RINGS  10
#define N_ANGLES 36
#define NP       (N_RINGS * N_ANGLES)   // 360 points per batch
#define PI_APPROX 3.1415926f

#define BLOCK  256        // 4 waves
#define WPB    4          // waves per block
#define CHUNK  1024       // targets staged per block
#define PPT    6          // point-slots per lane: 6*64 = 384 >= 360

// ---------------- kernel A: per-(batch, target-chunk) block --------------
// Each lane owns 6 point slots (l, l+64, ..., l+320). Waves split the staged
// CHUNK of targets; each wave-uniform ds_read_b128 broadcast feeds 6 points
// (24 FMA/MIN). Cross-chunk combination via global atomicMin on uint bits
// (d2 >= 0 after clamp, so uint order == float order). minbuf pre-set to
// 0xFFFFFFFF (UINT_MAX) by hipMemsetAsync before launch.
__global__ __launch_bounds__(BLOCK) void chamfer_minbuf(
    const float* __restrict__ pred,    // B x N_RINGS
    const float* __restrict__ target,  // B x N x 3
    unsigned int* __restrict__ minbuf, // B x NP (min d2, uint bits)
    int N, int chunks)
{
    __shared__ float4 t4[CHUNK];          // x, y, z, |t|^2
    __shared__ float  pm[WPB * NP];       // per-wave clamped partial mins
    __shared__ float  cs_c[N_ANGLES], cs_s[N_ANGLES];

    const int b   = blockIdx.x / chunks;
    const int cg  = blockIdx.x % chunks;
    const int n0  = cg * CHUNK;
    const int tid = threadIdx.x;
    const int cnt = min(CHUNK, N - n0);

    if (tid < N_ANGLES) {
        float angf = (float)(10 * tid) * (2.0f * PI_APPROX / 360.0f);
        double ang = (double)angf;
        cs_c[tid] = (float)cos(ang);
        cs_s[tid] = (float)sin(ang);
    }
    // stage target chunk: x, y, z, |t|^2
    for (int i = tid; i < cnt; i += BLOCK) {
        const float* t = target + ((size_t)b * N + (size_t)(n0 + i)) * 3;
        float x = t[0], y = t[1], z = t[2];
        t4[i] = make_float4(x, y, z, x * x + y * y + z * z);
    }
    __syncthreads();

    const int lane = tid & 63;
    const int w    = tid >> 6;

    // q = -2*p so inner pair = fma(qz,z, fma(qy,y, fma(qx,x, t2)))
    float qx[PPT], qy[PPT], qz[PPT], pp2[PPT], m[PPT];
    #pragma unroll
    for (int k = 0; k < PPT; ++k) {
        int s = lane + 64 * k;
        int j = s / N_ANGLES;
        int a = s - j * N_ANGLES;
        int jc = (j < N_RINGS) ? j : (N_RINGS - 1);   // clamp dummy slots
        float r  = pred[b * N_RINGS + jc];
        float px = -r * cs_c[a] + 0.04f;
        float py = 0.15f * (float)jc - 0.7f;
        float pz = r * cs_s[a];
        pp2[k] = px * px + py * py + pz * pz;
        qx[k] = -2.0f * px;
        qy[k] = -2.0f * py;
        qz[k] = -2.0f * pz;
        m[k]  = FLT_MAX;
    }

    // waves split the chunk; t4[k] is wave-uniform -> broadcast read
    #pragma unroll 4
    for (int k = w; k < cnt; k += WPB) {
        float4 t = t4[k];
        #pragma unroll
        for (int i = 0; i < PPT; ++i) {
            float h = fmaf(qz[i], t.z, t.w);
            h = fmaf(qy[i], t.y, h);
            h = fmaf(qx[i], t.x, h);
            m[i] = fminf(m[i], h);
        }
    }

    // finalize (add pp2, clamp) and publish per-wave partials
    #pragma unroll
    for (int k = 0; k < PPT; ++k) {
        int s = lane + 64 * k;
        if (s < NP) pm[w * NP + s] = fmaxf(pp2[k] + m[k], 0.0f);
    }
    __syncthreads();

    // cross-wave min, then one global atomicMin per point
    for (int p = tid; p < NP; p += BLOCK) {
        float v = fminf(fminf(pm[p], pm[NP + p]),
                        fminf(pm[2 * NP + p], pm[3 * NP + p]));
        atomicMin(&minbuf[b * NP + p], __float_as_uint(v));
    }
}

// ---------------- kernel B: mean over B*NP mins (L2-warm, 46 KB) ---------
__global__ __launch_bounds__(1024) void reduce_mean(
    const unsigned int* __restrict__ minbuf, float* __restrict__ out,
    int count)
{
    __shared__ double sm[16];
    const int tid = threadIdx.x;
    double s = 0.0;
    for (int i = tid; i < count; i += 1024)
        s += (double)__uint_as_float(minbuf[i]);
    #pragma unroll
    for (int off = 32; off > 0; off >>= 1)
        s += __shfl_down(s, off, 64);
    if ((tid & 63) == 0) sm[tid >> 6] = s;
    __syncthreads();
    if (tid == 0) {
        double tot = 0.0;
        for (int wv = 0; wv < 16; ++wv) tot += sm[wv];
        out[0] = (float)(tot / (double)count);
    }
}

extern "C" void kernel_launch(void* const* d_in, const int* in_sizes, int n_in,
                              void* d_out, int out_size, void* d_ws, size_t ws_size,
                              hipStream_t stream) {
    const float* pred   = (const float*)d_in[0];
    const float* target = (const float*)d_in[1];
    // d_in[2] (trans_feat) unused by the reference.

    const int B = in_sizes[0] / N_RINGS;
    const int N = in_sizes[1] / (3 * B);
    const int chunks = (N + CHUNK - 1) / CHUNK;   // 16 for N=16384
    const int count  = B * NP;                    // 11520

    unsigned int* minbuf = (unsigned int*)d_ws;
    float* out = (float*)d_out;

    // init minbuf to UINT_MAX (graph-capture-safe async memset)
    hipMemsetAsync(minbuf, 0xFF, (size_t)count * sizeof(unsigned int), stream);

    hipLaunchKernelGGL(chamfer_minbuf, dim3(B * chunks), dim3(BLOCK), 0, stream,
                       pred, target, minbuf, N, chunks);
    hipLaunchKernelGGL(reduce_mean, dim3(1), dim3(1024), 0, stream,
                       minbuf, out, count);
}